// Round 7
// baseline (29.996 us; speedup 1.0000x reference)
//
#include <hip/hip_runtime.h>

#define N_ 2
#define L_ 2048
#define H_ 8
#define NH_ 16
#define C_ 32
#define NC_ 64
#define EPS_ 1e-6f
#define DELTA_ 0.1f

#define CHSZ 4160                        // 65 rows (m=0..64) x 64 e, bf16 per chunk state
#define ST_SHORTS (NH_*NC_*CHSZ)
#define KV_SHORTS (NH_*L_*64)

typedef short s8v __attribute__((ext_vector_type(8)));
typedef short s4v __attribute__((ext_vector_type(4)));
typedef float f4v __attribute__((ext_vector_type(4)));

__device__ __forceinline__ float elup1(float x){ return x>0.f ? x+1.f : __expf(x); }
__device__ __forceinline__ short f2b(float x){            // f32 -> bf16 RNE
  unsigned u = __float_as_uint(x);
  return (short)((u + 0x7FFFu + ((u>>16)&1u)) >> 16);
}
__device__ __forceinline__ float b2f(short s){
  return __uint_as_float(((unsigned)(unsigned short)s) << 16);
}

// ---- Kernel A: stage K~ bf16 + V~^T bf16 to ws, chunk-state GEMM (MFMA), mu (fp32) ----
__global__ __launch_bounds__(256) void kA(const float* __restrict__ keys,
    const float* __restrict__ values, const float* __restrict__ mask,
    unsigned short* __restrict__ st, short* __restrict__ ktil,
    short* __restrict__ vtilT, float* __restrict__ mu)
{
  const int bid = blockIdx.x, c = bid & (NC_-1), nh = bid >> 6;
  const int n = nh >> 3, h = nh & 7, tid = threadIdx.x;
  const int lane = tid & 63, w = tid >> 6, r = lane & 15, g = lane >> 4;

  __shared__ __attribute__((aligned(16))) short Ktb[64][40];  // [e][t]
  __shared__ __attribute__((aligned(16))) short Vtb[80][40];  // [m][t], row64=1s, 65+=0
  __shared__ float prt[6][8][32];

  // stage 32 rows x 64 e
  #pragma unroll
  for (int i = 0; i < 2; ++i) {
    const int idx4 = tid + 256*i;                  // 512 float4s
    const int t = idx4 >> 4, e4 = (idx4 & 15) << 2;
    const int l = c*C_ + t;
    const size_t b = (((size_t)n*L_ + l)*H_ + h)*64 + e4;
    const float m0 = mask[n*L_ + l];
    const f4v kx = *(const f4v*)&keys[b];
    const f4v vx = *(const f4v*)&values[b];
    s4v kb4;
    #pragma unroll
    for (int j = 0; j < 4; ++j) kb4[j] = f2b(elup1(kx[j]) * m0);
    *(s4v*)&ktil[((size_t)nh*L_ + l)*64 + e4] = kb4;
    #pragma unroll
    for (int j = 0; j < 4; ++j) { Ktb[e4+j][t] = kb4[j]; Vtb[e4+j][t] = f2b(vx[j]); }
  }
  // Vtb rows 64..79: row 64 = ones, rest zero
  for (int idx = tid; idx < 16*40; idx += 256) {
    const int rr2 = idx/40, cc2 = idx - rr2*40;
    Vtb[64+rr2][cc2] = (rr2==0 && cc2<C_) ? (short)0x3F80 : (short)0;
  }
  __syncthreads();

  // V~^T out (chunk-transposed [m][t], vectorized from LDS): 64x32 shorts
  {
    const int m = tid >> 2, t8 = (tid & 3) << 3;
    *(s8v*)&vtilT[((size_t)bid*64 + m)*C_ + t8] = *(const s8v*)&Vtb[m][t8];
  }

  // S[m][e] = sum_t Vaug[t][m] * K~[t][e]   (K=32 -> single MFMA k-step)
  {
    f4v acc[5];
    #pragma unroll
    for (int j = 0; j < 5; ++j) acc[j] = (f4v)(0.f);
    const s8v a = *(const s8v*)&Ktb[w*16 + r][g*8];
    #pragma unroll
    for (int mj = 0; mj < 5; ++mj) {
      const s8v bb = *(const s8v*)&Vtb[mj*16 + r][g*8];
      acc[mj] = __builtin_amdgcn_mfma_f32_16x16x32_bf16(a, bb, acc[mj], 0, 0, 0);
    }
    unsigned short* sp = st + (size_t)bid*CHSZ;
    #pragma unroll
    for (int mj = 0; mj < 5; ++mj) {
      const int m = mj*16 + r;
      if (m <= 64) {
        s4v pk;
        #pragma unroll
        for (int j = 0; j < 4; ++j) pk[j] = f2b(acc[mj][j]);
        *(s4v*)&sp[(size_t)m*64 + w*16 + g*4] = pk;
      }
    }
  }

  // mu dot-products from global (L1/L2-hot), fp32: thread = (t, e-octet)
  {
    const int t = tid & 31, eq = tid >> 5;         // eq 0..7, 8 e's each
    const int l = c*C_ + t;
    const int l1 = (l+1 < L_) ? l+1 : l;
    const size_t b0 = (((size_t)n*L_ + l )*H_ + h)*64 + eq*8;
    const size_t b1 = (((size_t)n*L_ + l1)*H_ + h)*64 + eq*8;
    const float m0 = mask[n*L_ + l], m1 = mask[n*L_ + l1];
    float kk0=0.f,kk1=0.f,knn=0.f,vv0=0.f,vv1=0.f,vnn=0.f;
    #pragma unroll
    for (int j = 0; j < 8; j += 4) {
      const f4v ka = *(const f4v*)&keys[b0+j];
      const f4v kc = *(const f4v*)&keys[b1+j];
      const f4v va = *(const f4v*)&values[b0+j];
      const f4v vc = *(const f4v*)&values[b1+j];
      #pragma unroll
      for (int jj = 0; jj < 4; ++jj) {
        const float k0 = elup1(ka[jj])*m0, k1 = elup1(kc[jj])*m1;
        kk0 += k0*k0; kk1 += k1*k1; knn += k0*k1;
        const float v0 = va[jj], v1 = vc[jj];
        vv0 += v0*v0; vv1 += v1*v1; vnn += v0*v1;
      }
    }
    prt[0][eq][t]=kk0; prt[1][eq][t]=kk1; prt[2][eq][t]=knn;
    prt[3][eq][t]=vv0; prt[4][eq][t]=vv1; prt[5][eq][t]=vnn;
  }
  __syncthreads();
  if (tid < 32) {
    float s[6];
    #pragma unroll
    for (int q2 = 0; q2 < 6; ++q2) {
      float acc2 = 0.f;
      #pragma unroll
      for (int eq = 0; eq < 8; ++eq) acc2 += prt[q2][eq][tid];
      s[q2] = acc2;
    }
    const int j = c*C_ + tid;
    float mval = 0.f;
    if (j < L_-1) {
      const float base2 = s[0]*s[3];
      float diff2 = s[1]*s[4] - 2.f*s[2]*s[5] + base2;
      diff2 = fmaxf(diff2, 0.f);
      if (base2 > 0.f) {
        const float r4 = sqrtf(sqrtf(diff2/base2));
        const float om = 1.f - r4;
        mval = fminf(om*om, 1.f - DELTA_);
      } else {
        mval = 1.f - DELTA_;
      }
    }
    mu[(size_t)nh*L_ + j] = mval;
  }
}

// ---- Kernel BC: exclusive bf16 chunk prefix (fp32 accum) + momentum suffix scan ----
__global__ __launch_bounds__(256) void kBC(unsigned short* __restrict__ st,
    const float* __restrict__ mu, float* __restrict__ aw)
{
  const int bx = blockIdx.x, tid = threadIdx.x;
  if (bx < 260) {                                   // 260*256 = 16*CHSZ lanes
    const int id = bx*256 + tid;
    const int nh2 = id / CHSZ;
    const int elem = id - nh2*CHSZ;
    unsigned short* base = st + (size_t)nh2*NC_*CHSZ + elem;
    unsigned short rr[NC_];
    #pragma unroll
    for (int c2 = 0; c2 < NC_; ++c2) rr[c2] = base[(size_t)c2*CHSZ];
    float acc = 0.f;
    #pragma unroll
    for (int c2 = 0; c2 < NC_; ++c2) {
      const float v = b2f((short)rr[c2]);
      base[(size_t)c2*CHSZ] = (unsigned short)f2b(acc);
      acc += v;
    }
    return;
  }
  const int nh2 = bx - 260;
  const float* mup = mu + (size_t)nh2*L_;
  float* awp = aw + (size_t)nh2*L_;
  __shared__ float Psc[256], Qsc[256];
  float lm[8];
  #pragma unroll
  for (int i = 0; i < 8; ++i) lm[i] = mup[tid*8 + i];
  float p = 1.f, q = 0.f;
  #pragma unroll
  for (int i = 7; i >= 0; --i) { q = lm[i]*q + 1.f; p *= lm[i]; }
  Psc[tid] = p; Qsc[tid] = q;
  __syncthreads();
  for (int d = 1; d < 256; d <<= 1) {
    float pr = 1.f, qr = 0.f;
    const bool has = (tid + d) < 256;
    if (has) { pr = Psc[tid+d]; qr = Qsc[tid+d]; }
    __syncthreads();
    if (has) { const float np = p*pr, nq = p*qr + q; p = np; q = nq; Psc[tid] = p; Qsc[tid] = q; }
    __syncthreads();
  }
  float x = (tid == 255) ? 1.f : Psc[tid+1] + Qsc[tid+1];
  #pragma unroll
  for (int i = 7; i >= 0; --i) { x = lm[i]*x + 1.f; awp[tid*8+i] = x; }
}

// ---- Kernel D: QK^T + fused [Q|P]x[S0;Vaug] GEMM + out/Kn stores (C=32 tiles) ----
__global__ __launch_bounds__(256) void kD(const float* __restrict__ queries,
    const unsigned short* __restrict__ st, const short* __restrict__ ktil,
    const short* __restrict__ vtilT, const float* __restrict__ aw,
    float* __restrict__ out, float* __restrict__ kn)
{
  const int bid = blockIdx.x, c = bid & (NC_-1), nh = bid >> 6;
  const int n = nh >> 3, h = nh & 7, tid = threadIdx.x;
  const int lane = tid & 63, w = tid >> 6, r = lane & 15, g = lane >> 4;

  __shared__ __attribute__((aligned(16))) short Qb[32][72];    // [t][e]
  __shared__ __attribute__((aligned(16))) short Kb[32][72];    // [s][e]
  __shared__ __attribute__((aligned(16))) short Vtb[80][40];   // [m][t], row64=1s
  __shared__ __attribute__((aligned(16))) union {
    struct { short Pb[32][40]; short Sb[80][72]; } d;
    float outf[32][68];
  } U;
  __shared__ float Zl[32], al[32];

  // Q (fp32 -> bf16): 32x64
  #pragma unroll
  for (int i = 0; i < 2; ++i) {
    const int idx4 = tid + 256*i;
    const int t = idx4 >> 4, e4 = (idx4 & 15) << 2;
    const int l = c*C_ + t;
    const f4v qx = *(const f4v*)&queries[(((size_t)n*L_ + l)*H_ + h)*64 + e4];
    s4v qb4;
    #pragma unroll
    for (int j = 0; j < 4; ++j) qb4[j] = f2b(elup1(qx[j]));
    *(s4v*)&Qb[t][e4] = qb4;
  }
  // K~ copy: 32x64 shorts
  {
    const int t = tid >> 3, e8 = (tid & 7) << 3;
    *(s8v*)&Kb[t][e8] = *(const s8v*)&ktil[((size_t)nh*L_ + c*C_ + t)*64 + e8];
  }
  // V~^T copy: 64x32 shorts
  {
    const int m = tid >> 2, t8 = (tid & 3) << 3;
    *(s8v*)&Vtb[m][t8] = *(const s8v*)&vtilT[((size_t)bid*64 + m)*C_ + t8];
  }
  for (int idx = tid; idx < 16*40; idx += 256) {
    const int rr2 = idx/40, cc2 = idx - rr2*40;
    Vtb[64+rr2][cc2] = (rr2==0 && cc2<C_) ? (short)0x3F80 : (short)0;
  }
  // S0 copy (bf16) + zero rows 65..79
  {
    const unsigned short* sp = st + (size_t)bid*CHSZ;
    for (int idx = tid; idx < 520; idx += 256) {
      const int m = idx >> 3, e8 = (idx & 7) << 3;
      *(s8v*)&U.d.Sb[m][e8] = *(const s8v*)&sp[(size_t)m*64 + e8];
    }
    for (int idx = 520 + tid; idx < 640; idx += 256) {
      *(s8v*)&U.d.Sb[idx>>3][(idx&7)<<3] = (s8v)(0);
    }
  }
  if (tid < 32) al[tid] = aw[(size_t)nh*L_ + c*C_ + tid];
  __syncthreads();

  // QK^T: wave w -> (s-tile st2 = w>>1, t-tile tt2 = w&1); K=e=64 (2 steps)
  {
    const int st2 = w >> 1, tt2 = w & 1;
    f4v pacc = (f4v)(0.f);
    #pragma unroll
    for (int k2 = 0; k2 < 2; ++k2) {
      const s8v a = *(const s8v*)&Kb[st2*16 + r][k2*32 + g*8];
      const s8v bb = *(const s8v*)&Qb[tt2*16 + r][k2*32 + g*8];
      pacc = __builtin_amdgcn_mfma_f32_16x16x32_bf16(a, bb, pacc, 0, 0, 0);
    }
    const int t = tt2*16 + r;
    s4v pk;
    #pragma unroll
    for (int j = 0; j < 4; ++j) {
      const int s2 = st2*16 + g*4 + j;
      pk[j] = (s2 <= t) ? f2b(pacc[j]) : (short)0;
    }
    *(s4v*)&U.d.Pb[t][st2*16 + g*4] = pk;
  }
  __syncthreads();

  // out_aug[t][m]: wave w -> t-tile wt = w&1; m-tiles: w<2 -> {0,1,2}, w>=2 -> {3,4}
  // K = e(64, from Qb x Sb) + s(32, from Pb x Vtb) = 3 k-steps
  const int wt = w & 1;
  const int mbase = (w >> 1) * 3;
  f4v oacc[3];
  #pragma unroll
  for (int j = 0; j < 3; ++j) oacc[j] = (f4v)(0.f);
  #pragma unroll
  for (int k2 = 0; k2 < 3; ++k2) {
    const s8v a = (k2 < 2) ? *(const s8v*)&Qb[wt*16 + r][k2*32 + g*8]
                           : *(const s8v*)&U.d.Pb[wt*16 + r][g*8];
    #pragma unroll
    for (int mi = 0; mi < 3; ++mi) {
      const int mj = mbase + mi;
      if (mj < 5) {
        const s8v bb = (k2 < 2) ? *(const s8v*)&U.d.Sb[mj*16 + r][k2*32 + g*8]
                                : *(const s8v*)&Vtb[mj*16 + r][g*8];
        oacc[mi] = __builtin_amdgcn_mfma_f32_16x16x32_bf16(a, bb, oacc[mi], 0, 0, 0);
      }
    }
  }
  __syncthreads();                                  // Pb/Sb reads done -> outf may alias

  if (mbase == 3 && r == 0) {                       // mj==4 (denominator col), oacc[1]
    #pragma unroll
    for (int j = 0; j < 4; ++j) Zl[wt*16 + g*4 + j] = 1.f / (oacc[1][j] + EPS_);
  }
  #pragma unroll
  for (int mi = 0; mi < 3; ++mi) {
    const int mj = mbase + mi;
    if (mj < 4) {
      #pragma unroll
      for (int j = 0; j < 4; ++j)
        U.outf[wt*16 + g*4 + j][mj*16 + r] = oacc[mi][j];
    }
  }
  __syncthreads();

  #pragma unroll
  for (int i = 0; i < 2; ++i) {                     // out = outf * Z (nontemporal)
    const int idx4 = tid + 256*i;
    const int t = idx4 >> 4, m4 = (idx4 & 15) << 2, l = c*C_ + t;
    f4v v = *(const f4v*)&U.outf[t][m4];
    const float z = Zl[t];
    v[0] *= z; v[1] *= z; v[2] *= z; v[3] *= z;
    __builtin_nontemporal_store(v, (f4v*)&out[(((size_t)n*L_ + l)*H_ + h)*64 + m4]);
  }
  #pragma unroll
  for (int i = 0; i < 2; ++i) {                     // Kn = K~ * a (nontemporal)
    const int idx4 = tid + 256*i;
    const int t = idx4 >> 4, e4 = (idx4 & 15) << 2, l = c*C_ + t;
    const float a2 = al[t];
    const s4v kb4 = *(const s4v*)&Kb[t][e4];
    f4v o;
    #pragma unroll
    for (int j = 0; j < 4; ++j) o[j] = b2f(kb4[j]) * a2;
    __builtin_nontemporal_store(o, (f4v*)&kn[(((size_t)n*L_ + l)*H_ + h)*64 + e4]);
  }
}

extern "C" void kernel_launch(void* const* d_in, const int* in_sizes, int n_in,
                              void* d_out, int out_size, void* d_ws, size_t ws_size,
                              hipStream_t stream) {
  (void)in_sizes; (void)n_in; (void)out_size; (void)ws_size;
  const float* queries = (const float*)d_in[0];
  const float* keys    = (const float*)d_in[1];
  const float* values  = (const float*)d_in[2];
  const float* mask    = (const float*)d_in[3];
  float* out = (float*)d_out;
  float* kn  = out + (size_t)N_*L_*H_*64;

  unsigned short* st = (unsigned short*)d_ws;
  short* ktil = (short*)(st + ST_SHORTS);
  short* vtilT = ktil + KV_SHORTS;
  float* mu = (float*)(vtilT + KV_SHORTS);
  float* aw = mu + NH_*L_;

  hipLaunchKernelGGL(kA,  dim3(NH_*NC_), dim3(256), 0, stream,
                     keys, values, mask, st, ktil, vtilT, mu);
  hipLaunchKernelGGL(kBC, dim3(276),     dim3(256), 0, stream, st, mu, aw);
  hipLaunchKernelGGL(kD,  dim3(NH_*NC_), dim3(256), 0, stream,
                     queries, st, ktil, vtilT, aw, out, kn);
}

// Round 8
// 29.447 us; speedup vs baseline: 1.0186x; 1.0186x over previous
//
#include <hip/hip_runtime.h>

#define N_ 2
#define L_ 2048
#define H_ 8
#define NH_ 16
#define C_ 64
#define NC_ 32
#define EPS_ 1e-6f
#define DELTA_ 0.1f

#define CHSZ 4160                        // 65 rows (m=0..64) x 64 e, bf16 per chunk state
#define ST_SHORTS (NH_*NC_*CHSZ)
#define KV_SHORTS (NH_*L_*64)

typedef short s8v __attribute__((ext_vector_type(8)));
typedef short s4v __attribute__((ext_vector_type(4)));
typedef float f4v __attribute__((ext_vector_type(4)));

__device__ __forceinline__ float elup1(float x){ return x>0.f ? x+1.f : __expf(x); }
__device__ __forceinline__ short f2b(float x){            // f32 -> bf16 RNE
  unsigned u = __float_as_uint(x);
  return (short)((u + 0x7FFFu + ((u>>16)&1u)) >> 16);
}
__device__ __forceinline__ float b2f(short s){
  return __uint_as_float(((unsigned)(unsigned short)s) << 16);
}

// ---- Kernel A: stage K~ bf16 + V~^T bf16 to ws, chunk-state GEMM (MFMA), mu (fp32) ----
__global__ __launch_bounds__(256) void kA(const float* __restrict__ keys,
    const float* __restrict__ values, const float* __restrict__ mask,
    unsigned short* __restrict__ st, short* __restrict__ ktil,
    short* __restrict__ vtilT, float* __restrict__ mu)
{
  const int bid = blockIdx.x, c = bid & (NC_-1), nh = bid >> 5;
  const int n = nh >> 3, h = nh & 7, tid = threadIdx.x;
  const int lane = tid & 63, w = tid >> 6, r = lane & 15, g = lane >> 4;

  __shared__ __attribute__((aligned(16))) short Ktb[64][72];  // [e][t]
  __shared__ __attribute__((aligned(16))) short Vtb[80][72];  // [m][t], row64=1s
  __shared__ float prt[6][4][64];

  #pragma unroll
  for (int i = 0; i < 4; ++i) {
    const int idx4 = tid + 256*i;
    const int t = idx4 >> 4, e4 = (idx4 & 15) << 2;
    const int l = c*C_ + t;
    const size_t b = (((size_t)n*L_ + l)*H_ + h)*64 + e4;
    const float m0 = mask[n*L_ + l];
    const f4v kx = *(const f4v*)&keys[b];
    const f4v vx = *(const f4v*)&values[b];
    s4v kb4;
    #pragma unroll
    for (int j = 0; j < 4; ++j) kb4[j] = f2b(elup1(kx[j]) * m0);
    *(s4v*)&ktil[((size_t)nh*L_ + l)*64 + e4] = kb4;
    #pragma unroll
    for (int j = 0; j < 4; ++j) { Ktb[e4+j][t] = kb4[j]; Vtb[e4+j][t] = f2b(vx[j]); }
  }
  if (tid < 64) Vtb[64][tid] = (short)0x3F80;       // 1.0 bf16
  __syncthreads();

  // V~^T out (chunk-transposed [m][t], vectorized from LDS)
  #pragma unroll
  for (int i = 0; i < 2; ++i) {
    const int idx8 = tid + 256*i;
    const int m = idx8 >> 3, t8 = (idx8 & 7) << 3;
    *(s8v*)&vtilT[((size_t)bid*64 + m)*64 + t8] = *(const s8v*)&Vtb[m][t8];
  }

  // S[m][e] = sum_t Vaug[t][m] * K~[t][e]
  {
    f4v acc[5];
    #pragma unroll
    for (int j = 0; j < 5; ++j) acc[j] = (f4v)(0.f);
    #pragma unroll
    for (int k2 = 0; k2 < 2; ++k2) {
      const s8v a = *(const s8v*)&Ktb[w*16 + r][k2*32 + g*8];
      #pragma unroll
      for (int mj = 0; mj < 5; ++mj) {
        const s8v bb = *(const s8v*)&Vtb[mj*16 + r][k2*32 + g*8];
        acc[mj] = __builtin_amdgcn_mfma_f32_16x16x32_bf16(a, bb, acc[mj], 0, 0, 0);
      }
    }
    unsigned short* sp = st + (size_t)bid*CHSZ;
    #pragma unroll
    for (int mj = 0; mj < 5; ++mj) {
      const int m = mj*16 + r;
      if (m <= 64) {
        s4v pk;
        #pragma unroll
        for (int j = 0; j < 4; ++j) pk[j] = f2b(acc[mj][j]);
        *(s4v*)&sp[(size_t)m*64 + w*16 + g*4] = pk;
      }
    }
  }

  // mu dot-products from global (L1/L2-hot), fp32
  {
    const int t = lane, eq = w;
    const int l = c*C_ + t;
    const int l1 = (l+1 < L_) ? l+1 : l;
    const size_t b0 = (((size_t)n*L_ + l )*H_ + h)*64 + eq*16;
    const size_t b1 = (((size_t)n*L_ + l1)*H_ + h)*64 + eq*16;
    const float m0 = mask[n*L_ + l], m1 = mask[n*L_ + l1];
    float kk0=0.f,kk1=0.f,knn=0.f,vv0=0.f,vv1=0.f,vnn=0.f;
    #pragma unroll
    for (int j = 0; j < 16; j += 4) {
      const f4v ka = *(const f4v*)&keys[b0+j];
      const f4v kc = *(const f4v*)&keys[b1+j];
      const f4v va = *(const f4v*)&values[b0+j];
      const f4v vc = *(const f4v*)&values[b1+j];
      #pragma unroll
      for (int jj = 0; jj < 4; ++jj) {
        const float k0 = elup1(ka[jj])*m0, k1 = elup1(kc[jj])*m1;
        kk0 += k0*k0; kk1 += k1*k1; knn += k0*k1;
        const float v0 = va[jj], v1 = vc[jj];
        vv0 += v0*v0; vv1 += v1*v1; vnn += v0*v1;
      }
    }
    prt[0][eq][t]=kk0; prt[1][eq][t]=kk1; prt[2][eq][t]=knn;
    prt[3][eq][t]=vv0; prt[4][eq][t]=vv1; prt[5][eq][t]=vnn;
  }
  __syncthreads();
  if (tid < 64) {
    float s[6];
    #pragma unroll
    for (int q2 = 0; q2 < 6; ++q2)
      s[q2] = prt[q2][0][tid]+prt[q2][1][tid]+prt[q2][2][tid]+prt[q2][3][tid];
    const int j = c*C_ + tid;
    float mval = 0.f;
    if (j < L_-1) {
      const float base2 = s[0]*s[3];
      float diff2 = s[1]*s[4] - 2.f*s[2]*s[5] + base2;
      diff2 = fmaxf(diff2, 0.f);
      if (base2 > 0.f) {
        const float r4 = sqrtf(sqrtf(diff2/base2));
        const float om = 1.f - r4;
        mval = fminf(om*om, 1.f - DELTA_);
      } else {
        mval = 1.f - DELTA_;
      }
    }
    mu[(size_t)nh*L_ + j] = mval;
  }
}

// ---- Kernel BC: exclusive bf16 chunk prefix (fp32 accum) + momentum suffix scan ----
__global__ __launch_bounds__(256) void kBC(unsigned short* __restrict__ st,
    const float* __restrict__ mu, float* __restrict__ aw)
{
  const int bx = blockIdx.x, tid = threadIdx.x;
  if (bx < 260) {
    const int id = bx*256 + tid;
    const int nh2 = id / CHSZ;
    const int elem = id - nh2*CHSZ;
    unsigned short* base = st + (size_t)nh2*NC_*CHSZ + elem;
    unsigned short rr[NC_];
    #pragma unroll
    for (int c2 = 0; c2 < NC_; ++c2) rr[c2] = base[(size_t)c2*CHSZ];
    float acc = 0.f;
    #pragma unroll
    for (int c2 = 0; c2 < NC_; ++c2) {
      const float v = b2f((short)rr[c2]);
      base[(size_t)c2*CHSZ] = (unsigned short)f2b(acc);
      acc += v;
    }
    return;
  }
  const int nh2 = bx - 260;
  const float* mup = mu + (size_t)nh2*L_;
  float* awp = aw + (size_t)nh2*L_;
  __shared__ float Psc[256], Qsc[256];
  float lm[8];
  #pragma unroll
  for (int i = 0; i < 8; ++i) lm[i] = mup[tid*8 + i];
  float p = 1.f, q = 0.f;
  #pragma unroll
  for (int i = 7; i >= 0; --i) { q = lm[i]*q + 1.f; p *= lm[i]; }
  Psc[tid] = p; Qsc[tid] = q;
  __syncthreads();
  for (int d = 1; d < 256; d <<= 1) {
    float pr = 1.f, qr = 0.f;
    const bool has = (tid + d) < 256;
    if (has) { pr = Psc[tid+d]; qr = Qsc[tid+d]; }
    __syncthreads();
    if (has) { const float np = p*pr, nq = p*qr + q; p = np; q = nq; Psc[tid] = p; Qsc[tid] = q; }
    __syncthreads();
  }
  float x = (tid == 255) ? 1.f : Psc[tid+1] + Qsc[tid+1];
  #pragma unroll
  for (int i = 7; i >= 0; --i) { x = lm[i]*x + 1.f; awp[tid*8+i] = x; }
}

// ---- Kernel D: QK^T + fused GEMM; S0/V operands gathered from global; direct stores ----
__global__ __launch_bounds__(256) void kD(const float* __restrict__ queries,
    const unsigned short* __restrict__ st, const short* __restrict__ ktil,
    const short* __restrict__ vtilT, const float* __restrict__ aw,
    float* __restrict__ out, float* __restrict__ kn)
{
  const int bid = blockIdx.x, c = bid & (NC_-1), nh = bid >> 5;
  const int n = nh >> 3, h = nh & 7, tid = threadIdx.x;
  const int lane = tid & 63, w = tid >> 6, r = lane & 15, g = lane >> 4;

  __shared__ __attribute__((aligned(16))) short Qb[64][72];    // [t][e]
  __shared__ __attribute__((aligned(16))) short Kb[64][72];    // [s][e]
  __shared__ __attribute__((aligned(16))) short Pb[64][72];    // [t][s]
  __shared__ float al[64];

  const unsigned short* sp = st + (size_t)bid*CHSZ;
  const short* vp = vtilT + (size_t)bid*64*64;

  // S0 B-fragments from global (L2-hot), incl. z0 row 64 (r==0 only)
  s8v sfrag[2][4], srow64[2];
  const s8v zero8 = (s8v)(0);
  #pragma unroll
  for (int k2 = 0; k2 < 2; ++k2) {
    #pragma unroll
    for (int mj = 0; mj < 4; ++mj)
      sfrag[k2][mj] = *(const s8v*)&sp[(size_t)(mj*16 + r)*64 + k2*32 + g*8];
    srow64[k2] = (r == 0) ? *(const s8v*)&sp[(size_t)64*64 + k2*32 + g*8] : zero8;
  }

  // Q (fp32 -> bf16, nontemporal)
  #pragma unroll
  for (int i = 0; i < 4; ++i) {
    const int idx4 = tid + 256*i;
    const int t = idx4 >> 4, e4 = (idx4 & 15) << 2;
    const int l = c*C_ + t;
    const f4v qx = __builtin_nontemporal_load(
        (const f4v*)&queries[(((size_t)n*L_ + l)*H_ + h)*64 + e4]);
    s4v qb4;
    #pragma unroll
    for (int j = 0; j < 4; ++j) qb4[j] = f2b(elup1(qx[j]));
    *(s4v*)&Qb[t][e4] = qb4;
  }
  // K~ copy (bf16 row-major)
  for (int idx = tid; idx < 512; idx += 256) {
    const int t = idx >> 3, e8 = (idx & 7) << 3;
    *(s8v*)&Kb[t][e8] = *(const s8v*)&ktil[((size_t)nh*L_ + c*C_ + t)*64 + e8];
  }
  if (tid < 64) al[tid] = aw[(size_t)nh*L_ + c*C_ + tid];
  __syncthreads();

  // QK^T (M=s, N=t, K=e) -> Pb[t][s], causal-masked bf16
  {
    f4v pacc[4];
    #pragma unroll
    for (int tj = 0; tj < 4; ++tj) pacc[tj] = (f4v)(0.f);
    #pragma unroll
    for (int k2 = 0; k2 < 2; ++k2) {
      const s8v a = *(const s8v*)&Kb[w*16 + r][k2*32 + g*8];
      #pragma unroll
      for (int tj = 0; tj < 4; ++tj) {
        const s8v bb = *(const s8v*)&Qb[tj*16 + r][k2*32 + g*8];
        pacc[tj] = __builtin_amdgcn_mfma_f32_16x16x32_bf16(a, bb, pacc[tj], 0, 0, 0);
      }
    }
    #pragma unroll
    for (int tj = 0; tj < 4; ++tj) {
      const int t = tj*16 + r;
      s4v pk;
      #pragma unroll
      for (int j = 0; j < 4; ++j) {
        const int s2 = w*16 + g*4 + j;
        pk[j] = (s2 <= t) ? f2b(pacc[tj][j]) : (short)0;
      }
      *(s4v*)&Pb[t][w*16 + g*4] = pk;
    }
  }

  // V^T B-fragments from global (pacc now dead; loads overlap barrier drain)
  s8v vfrag[2][4], vones;
  #pragma unroll
  for (int k2 = 0; k2 < 2; ++k2)
    #pragma unroll
    for (int mj = 0; mj < 4; ++mj)
      vfrag[k2][mj] = *(const s8v*)&vp[(size_t)(mj*16 + r)*64 + k2*32 + g*8];
  {
    s8v o;
    #pragma unroll
    for (int j = 0; j < 8; ++j) o[j] = (short)0x3F80;
    vones = (r == 0) ? o : zero8;
  }
  __syncthreads();

  // out_aug[t][m] = sum_e Q S0 + sum_s P Vaug; mj==4 col 0 = denominator
  f4v oacc[5];
  #pragma unroll
  for (int j = 0; j < 5; ++j) oacc[j] = (f4v)(0.f);
  #pragma unroll
  for (int k2 = 0; k2 < 4; ++k2) {
    const s8v a = (k2 < 2) ? *(const s8v*)&Qb[w*16 + r][k2*32 + g*8]
                           : *(const s8v*)&Pb[w*16 + r][(k2-2)*32 + g*8];
    #pragma unroll
    for (int mj = 0; mj < 5; ++mj) {
      const s8v bb = (k2 < 2) ? ((mj < 4) ? sfrag[k2][mj] : srow64[k2])
                              : ((mj < 4) ? vfrag[k2-2][mj] : vones);
      oacc[mj] = __builtin_amdgcn_mfma_f32_16x16x32_bf16(a, bb, oacc[mj], 0, 0, 0);
    }
  }

  // direct epilogue: z via intra-wave shfl broadcast from r==0 lanes
  {
    float z[4];
    #pragma unroll
    for (int j = 0; j < 4; ++j) {
      const float dj = __shfl(oacc[4][j], g << 4);
      z[j] = 1.f / (dj + EPS_);
    }
    float* obase = out + (((size_t)n*L_ + c*C_ + w*16)*H_ + h)*64;
    #pragma unroll
    for (int mj = 0; mj < 4; ++mj)
      #pragma unroll
      for (int j = 0; j < 4; ++j)
        __builtin_nontemporal_store(oacc[mj][j] * z[j],
            &obase[(size_t)(g*4 + j)*H_*64 + mj*16 + r]);
  }
  // Kn = K~ * a (nontemporal)
  #pragma unroll
  for (int i = 0; i < 4; ++i) {
    const int idx4 = tid + 256*i;
    const int t = idx4 >> 4, e4 = (idx4 & 15) << 2, l = c*C_ + t;
    const float a2 = al[t];
    const s4v kb4 = *(const s4v*)&Kb[t][e4];
    f4v o;
    #pragma unroll
    for (int j = 0; j < 4; ++j) o[j] = b2f(kb4[j]) * a2;
    __builtin_nontemporal_store(o, (f4v*)&kn[(((size_t)n*L_ + l)*H_ + h)*64 + e4]);
  }
}

extern "C" void kernel_launch(void* const* d_in, const int* in_sizes, int n_in,
                              void* d_out, int out_size, void* d_ws, size_t ws_size,
                              hipStream_t stream) {
  (void)in_sizes; (void)n_in; (void)out_size; (void)ws_size;
  const float* queries = (const float*)d_in[0];
  const float* keys    = (const float*)d_in[1];
  const float* values  = (const float*)d_in[2];
  const float* mask    = (const float*)d_in[3];
  float* out = (float*)d_out;
  float* kn  = out + (size_t)N_*L_*H_*64;

  unsigned short* st = (unsigned short*)d_ws;
  short* ktil = (short*)(st + ST_SHORTS);
  short* vtilT = ktil + KV_SHORTS;
  float* mu = (float*)(vtilT + KV_SHORTS);
  float* aw = mu + NH_*L_;

  hipLaunchKernelGGL(kA,  dim3(NH_*NC_), dim3(256), 0, stream,
                     keys, values, mask, st, ktil, vtilT, mu);
  hipLaunchKernelGGL(kBC, dim3(276),     dim3(256), 0, stream, st, mu, aw);
  hipLaunchKernelGGL(kD,  dim3(NH_*NC_), dim3(256), 0, stream,
                     queries, st, ktil, vtilT, aw, out, kn);
}

// Round 9
// 26.658 us; speedup vs baseline: 1.1252x; 1.1047x over previous
//
#include <hip/hip_runtime.h>

#define N_ 2
#define L_ 2048
#define H_ 8
#define NH_ 16
#define C_ 64
#define NC_ 32
#define EPS_ 1e-6f
#define DELTA_ 0.1f

#define CHSZ 4160                        // 65 rows (m=0..64) x 64 e, bf16 per chunk state
#define ST_SHORTS (NH_*NC_*CHSZ)
#define KV_SHORTS (NH_*L_*64)

typedef short s8v __attribute__((ext_vector_type(8)));
typedef short s4v __attribute__((ext_vector_type(4)));
typedef float f4v __attribute__((ext_vector_type(4)));

__device__ __forceinline__ float elup1(float x){ return x>0.f ? x+1.f : __expf(x); }
__device__ __forceinline__ short f2b(float x){            // f32 -> bf16 RNE
  unsigned u = __float_as_uint(x);
  return (short)((u + 0x7FFFu + ((u>>16)&1u)) >> 16);
}
__device__ __forceinline__ float b2f(short s){
  return __uint_as_float(((unsigned)(unsigned short)s) << 16);
}

// ---- Kernel A (512 thr): stage K~/V~^T, state GEMM (waves 0-3) || mu (waves 4-7) ----
__global__ __launch_bounds__(512) void kA(const float* __restrict__ keys,
    const float* __restrict__ values, const float* __restrict__ mask,
    unsigned short* __restrict__ st, short* __restrict__ ktil,
    short* __restrict__ vtilT, float* __restrict__ mu)
{
  const int bid = blockIdx.x, c = bid & (NC_-1), nh = bid >> 5;
  const int n = nh >> 3, h = nh & 7, tid = threadIdx.x;

  __shared__ __attribute__((aligned(16))) short Ktb[64][72];  // [e][t]
  __shared__ __attribute__((aligned(16))) short Vtb[80][72];  // [m][t], row64=1s
  __shared__ float prt[6][4][64];

  #pragma unroll
  for (int i = 0; i < 2; ++i) {
    const int idx4 = tid + 512*i;                  // 1024 float4s
    const int t = idx4 >> 4, e4 = (idx4 & 15) << 2;
    const int l = c*C_ + t;
    const size_t b = (((size_t)n*L_ + l)*H_ + h)*64 + e4;
    const float m0 = mask[n*L_ + l];
    const f4v kx = *(const f4v*)&keys[b];
    const f4v vx = *(const f4v*)&values[b];
    s4v kb4;
    #pragma unroll
    for (int j = 0; j < 4; ++j) kb4[j] = f2b(elup1(kx[j]) * m0);
    *(s4v*)&ktil[((size_t)nh*L_ + l)*64 + e4] = kb4;
    #pragma unroll
    for (int j = 0; j < 4; ++j) { Ktb[e4+j][t] = kb4[j]; Vtb[e4+j][t] = f2b(vx[j]); }
  }
  if (tid < 64) Vtb[64][tid] = (short)0x3F80;       // 1.0 bf16
  __syncthreads();

  // V~^T out (512 s8v, one per thread)
  {
    const int m = tid >> 3, t8 = (tid & 7) << 3;
    *(s8v*)&vtilT[((size_t)bid*64 + m)*64 + t8] = *(const s8v*)&Vtb[m][t8];
  }

  if (tid < 256) {
    // ---- waves 0-3: S[m][e] = sum_t Vaug[t][m] * K~[t][e] ----
    const int lane = tid & 63, w = tid >> 6, r = lane & 15, g = lane >> 4;
    f4v acc[5];
    #pragma unroll
    for (int j = 0; j < 5; ++j) acc[j] = (f4v)(0.f);
    #pragma unroll
    for (int k2 = 0; k2 < 2; ++k2) {
      const s8v a = *(const s8v*)&Ktb[w*16 + r][k2*32 + g*8];
      #pragma unroll
      for (int mj = 0; mj < 5; ++mj) {
        const s8v bb = *(const s8v*)&Vtb[mj*16 + r][k2*32 + g*8];
        acc[mj] = __builtin_amdgcn_mfma_f32_16x16x32_bf16(a, bb, acc[mj], 0, 0, 0);
      }
    }
    unsigned short* sp = st + (size_t)bid*CHSZ;
    #pragma unroll
    for (int mj = 0; mj < 5; ++mj) {
      const int m = mj*16 + r;
      if (m <= 64) {
        s4v pk;
        #pragma unroll
        for (int j = 0; j < 4; ++j) pk[j] = f2b(acc[mj][j]);
        *(s4v*)&sp[(size_t)m*64 + w*16 + g*4] = pk;
      }
    }
  } else {
    // ---- waves 4-7: mu dot-product partials (global, L2-hot, fp32) ----
    const int tid2 = tid - 256;
    const int t = tid2 & 63, eq = tid2 >> 6;
    const int l = c*C_ + t;
    const int l1 = (l+1 < L_) ? l+1 : l;
    const size_t b0 = (((size_t)n*L_ + l )*H_ + h)*64 + eq*16;
    const size_t b1 = (((size_t)n*L_ + l1)*H_ + h)*64 + eq*16;
    const float m0 = mask[n*L_ + l], m1 = mask[n*L_ + l1];
    float kk0=0.f,kk1=0.f,knn=0.f,vv0=0.f,vv1=0.f,vnn=0.f;
    #pragma unroll
    for (int j = 0; j < 16; j += 4) {
      const f4v ka = *(const f4v*)&keys[b0+j];
      const f4v kc = *(const f4v*)&keys[b1+j];
      const f4v va = *(const f4v*)&values[b0+j];
      const f4v vc = *(const f4v*)&values[b1+j];
      #pragma unroll
      for (int jj = 0; jj < 4; ++jj) {
        const float k0 = elup1(ka[jj])*m0, k1 = elup1(kc[jj])*m1;
        kk0 += k0*k0; kk1 += k1*k1; knn += k0*k1;
        const float v0 = va[jj], v1 = vc[jj];
        vv0 += v0*v0; vv1 += v1*v1; vnn += v0*v1;
      }
    }
    prt[0][eq][t]=kk0; prt[1][eq][t]=kk1; prt[2][eq][t]=knn;
    prt[3][eq][t]=vv0; prt[4][eq][t]=vv1; prt[5][eq][t]=vnn;
  }
  __syncthreads();
  if (tid < 64) {
    float s[6];
    #pragma unroll
    for (int q2 = 0; q2 < 6; ++q2)
      s[q2] = prt[q2][0][tid]+prt[q2][1][tid]+prt[q2][2][tid]+prt[q2][3][tid];
    const int j = c*C_ + tid;
    float mval = 0.f;
    if (j < L_-1) {
      const float base2 = s[0]*s[3];
      float diff2 = s[1]*s[4] - 2.f*s[2]*s[5] + base2;
      diff2 = fmaxf(diff2, 0.f);
      if (base2 > 0.f) {
        const float r4 = sqrtf(sqrtf(diff2/base2));
        const float om = 1.f - r4;
        mval = fminf(om*om, 1.f - DELTA_);
      } else {
        mval = 1.f - DELTA_;
      }
    }
    mu[(size_t)nh*L_ + j] = mval;
  }
}

// ---- Kernel BC: exclusive bf16 chunk prefix (fp32 accum) + momentum suffix scan ----
__global__ __launch_bounds__(256) void kBC(unsigned short* __restrict__ st,
    const float* __restrict__ mu, float* __restrict__ aw)
{
  const int bx = blockIdx.x, tid = threadIdx.x;
  if (bx < 260) {
    const int id = bx*256 + tid;
    const int nh2 = id / CHSZ;
    const int elem = id - nh2*CHSZ;
    unsigned short* base = st + (size_t)nh2*NC_*CHSZ + elem;
    unsigned short rr[NC_];
    #pragma unroll
    for (int c2 = 0; c2 < NC_; ++c2) rr[c2] = base[(size_t)c2*CHSZ];
    float acc = 0.f;
    #pragma unroll
    for (int c2 = 0; c2 < NC_; ++c2) {
      const float v = b2f((short)rr[c2]);
      base[(size_t)c2*CHSZ] = (unsigned short)f2b(acc);
      acc += v;
    }
    return;
  }
  const int nh2 = bx - 260;
  const float* mup = mu + (size_t)nh2*L_;
  float* awp = aw + (size_t)nh2*L_;
  __shared__ float Psc[256], Qsc[256];
  float lm[8];
  #pragma unroll
  for (int i = 0; i < 8; ++i) lm[i] = mup[tid*8 + i];
  float p = 1.f, q = 0.f;
  #pragma unroll
  for (int i = 7; i >= 0; --i) { q = lm[i]*q + 1.f; p *= lm[i]; }
  Psc[tid] = p; Qsc[tid] = q;
  __syncthreads();
  for (int d = 1; d < 256; d <<= 1) {
    float pr = 1.f, qr = 0.f;
    const bool has = (tid + d) < 256;
    if (has) { pr = Psc[tid+d]; qr = Qsc[tid+d]; }
    __syncthreads();
    if (has) { const float np = p*pr, nq = p*qr + q; p = np; q = nq; Psc[tid] = p; Qsc[tid] = q; }
    __syncthreads();
  }
  float x = (tid == 255) ? 1.f : Psc[tid+1] + Qsc[tid+1];
  #pragma unroll
  for (int i = 7; i >= 0; --i) { x = lm[i]*x + 1.f; awp[tid*8+i] = x; }
}

// ---- Kernel D (512 thr): QK^T (8-way) + out-GEMM (8-way) + coalesced epilogue ----
__global__ __launch_bounds__(512) void kD(const float* __restrict__ queries,
    const unsigned short* __restrict__ st, const short* __restrict__ ktil,
    const short* __restrict__ vtilT, const float* __restrict__ aw,
    float* __restrict__ out, float* __restrict__ kn)
{
  const int bid = blockIdx.x, c = bid & (NC_-1), nh = bid >> 5;
  const int n = nh >> 3, h = nh & 7, tid = threadIdx.x;
  const int lane = tid & 63, w = tid >> 6, r = lane & 15, g = lane >> 4;
  const int tt = w & 3, mg = w >> 2;     // roles: (s-tile,t-half) for QK^T; (t-tile,m-group) for GEMM

  __shared__ __attribute__((aligned(16))) short Qb[64][72];    // [t][e]
  __shared__ __attribute__((aligned(16))) short Kb[64][72];    // [s][e]
  __shared__ __attribute__((aligned(16))) union {
    short Pb[64][72];                                          // [t][s]
    float outf[64][68];
  } U;
  __shared__ float Zl[64], al[64];

  const unsigned short* sp = st + (size_t)bid*CHSZ;
  const short* vp = vtilT + (size_t)bid*4096;
  const s8v zero8 = (s8v)(0);

  // per-wave S0 B-fragments (global, L2-hot): mg0 -> mj{0,1,2}; mg1 -> mj{3}, z0-row
  s8v sfrag[2][3], srow64[2];
  #pragma unroll
  for (int k2 = 0; k2 < 2; ++k2) {
    if (mg == 0) {
      #pragma unroll
      for (int mi = 0; mi < 3; ++mi)
        sfrag[k2][mi] = *(const s8v*)&sp[(size_t)(mi*16 + r)*64 + k2*32 + g*8];
      srow64[k2] = zero8;
    } else {
      sfrag[k2][0] = *(const s8v*)&sp[(size_t)(48 + r)*64 + k2*32 + g*8];
      srow64[k2] = (r == 0) ? *(const s8v*)&sp[(size_t)64*64 + k2*32 + g*8] : zero8;
      sfrag[k2][1] = zero8; sfrag[k2][2] = zero8;
    }
  }

  // stage Qb (fp32 -> bf16, nontemporal), Kb, al
  #pragma unroll
  for (int i = 0; i < 2; ++i) {
    const int idx4 = tid + 512*i;
    const int t = idx4 >> 4, e4 = (idx4 & 15) << 2;
    const int l = c*C_ + t;
    const f4v qx = __builtin_nontemporal_load(
        (const f4v*)&queries[(((size_t)n*L_ + l)*H_ + h)*64 + e4]);
    s4v qb4;
    #pragma unroll
    for (int j = 0; j < 4; ++j) qb4[j] = f2b(elup1(qx[j]));
    *(s4v*)&Qb[t][e4] = qb4;
  }
  {
    const int t = tid >> 3, e8 = (tid & 7) << 3;
    *(s8v*)&Kb[t][e8] = *(const s8v*)&ktil[((size_t)nh*L_ + c*C_ + t)*64 + e8];
  }
  if (tid < 64) al[tid] = aw[(size_t)nh*L_ + c*C_ + tid];
  __syncthreads();

  // QK^T: wave = (s-tile ss=tt, t-half th=mg); 4 MFMAs; skip fully-masked pairs
  {
    const int ss = tt, th = mg;
    const bool live = (ss*16) <= (th*32 + 31);
    f4v pacc[2];
    pacc[0] = (f4v)(0.f); pacc[1] = (f4v)(0.f);
    if (live) {
      #pragma unroll
      for (int k2 = 0; k2 < 2; ++k2) {
        const s8v a = *(const s8v*)&Kb[ss*16 + r][k2*32 + g*8];
        #pragma unroll
        for (int tj2 = 0; tj2 < 2; ++tj2) {
          const s8v bb = *(const s8v*)&Qb[(th*2 + tj2)*16 + r][k2*32 + g*8];
          pacc[tj2] = __builtin_amdgcn_mfma_f32_16x16x32_bf16(a, bb, pacc[tj2], 0, 0, 0);
        }
      }
    }
    #pragma unroll
    for (int tj2 = 0; tj2 < 2; ++tj2) {
      const int t = (th*2 + tj2)*16 + r;
      s4v pk;
      #pragma unroll
      for (int j = 0; j < 4; ++j) {
        const int s2 = ss*16 + g*4 + j;
        pk[j] = (live && s2 <= t) ? f2b(pacc[tj2][j]) : (short)0;
      }
      *(s4v*)&U.Pb[t][ss*16 + g*4] = pk;
    }
  }

  // per-wave V^T B-fragments (global, L2-hot)
  s8v vfrag[2][3], vones;
  #pragma unroll
  for (int k2 = 0; k2 < 2; ++k2) {
    if (mg == 0) {
      #pragma unroll
      for (int mi = 0; mi < 3; ++mi)
        vfrag[k2][mi] = *(const s8v*)&vp[(size_t)(mi*16 + r)*64 + k2*32 + g*8];
    } else {
      vfrag[k2][0] = *(const s8v*)&vp[(size_t)(48 + r)*64 + k2*32 + g*8];
      vfrag[k2][1] = zero8; vfrag[k2][2] = zero8;
    }
  }
  {
    s8v o;
    #pragma unroll
    for (int j = 0; j < 8; ++j) o[j] = (short)0x3F80;
    vones = (r == 0 && mg == 1) ? o : zero8;
  }
  __syncthreads();

  // out-GEMM: wave = (t-tile tt, m-group mg); mg0: mj{0,1,2}, mg1: mj{3,4(denom)}
  const int nmj = (mg == 0) ? 3 : 2;
  f4v oacc[3];
  #pragma unroll
  for (int j = 0; j < 3; ++j) oacc[j] = (f4v)(0.f);
  #pragma unroll
  for (int k2 = 0; k2 < 4; ++k2) {
    const s8v a = (k2 < 2) ? *(const s8v*)&Qb[tt*16 + r][k2*32 + g*8]
                           : *(const s8v*)&U.Pb[tt*16 + r][(k2-2)*32 + g*8];
    #pragma unroll
    for (int mi = 0; mi < 3; ++mi) {
      if (mi < nmj) {
        s8v bb;
        if (k2 < 2) bb = (mg == 1 && mi == 1) ? srow64[k2] : sfrag[k2][mi];
        else        bb = (mg == 1 && mi == 1) ? vones      : vfrag[k2-2][mi];
        oacc[mi] = __builtin_amdgcn_mfma_f32_16x16x32_bf16(a, bb, oacc[mi], 0, 0, 0);
      }
    }
  }
  __syncthreads();                                  // Pb reads done -> outf may alias

  if (mg == 1 && r == 0) {
    #pragma unroll
    for (int j = 0; j < 4; ++j) Zl[tt*16 + g*4 + j] = 1.f / (oacc[1][j] + EPS_);
  }
  #pragma unroll
  for (int mi = 0; mi < 3; ++mi) {
    const int mjg = mg*3 + mi;
    if (mi < nmj && mjg < 4) {
      #pragma unroll
      for (int j = 0; j < 4; ++j)
        U.outf[tt*16 + g*4 + j][mjg*16 + r] = oacc[mi][j];
    }
  }
  __syncthreads();

  #pragma unroll
  for (int i = 0; i < 2; ++i) {                     // out = outf * Z (nontemporal)
    const int idx4 = tid + 512*i;
    const int t = idx4 >> 4, m4 = (idx4 & 15) << 2, l = c*C_ + t;
    f4v v = *(const f4v*)&U.outf[t][m4];
    const float z = Zl[t];
    v[0] *= z; v[1] *= z; v[2] *= z; v[3] *= z;
    __builtin_nontemporal_store(v, (f4v*)&out[(((size_t)n*L_ + l)*H_ + h)*64 + m4]);
  }
  #pragma unroll
  for (int i = 0; i < 2; ++i) {                     // Kn = K~ * a (nontemporal)
    const int idx4 = tid + 512*i;
    const int t = idx4 >> 4, e4 = (idx4 & 15) << 2, l = c*C_ + t;
    const float a2 = al[t];
    const s4v kb4 = *(const s4v*)&Kb[t][e4];
    f4v o;
    #pragma unroll
    for (int j = 0; j < 4; ++j) o[j] = b2f(kb4[j]) * a2;
    __builtin_nontemporal_store(o, (f4v*)&kn[(((size_t)n*L_ + l)*H_ + h)*64 + e4]);
  }
}

extern "C" void kernel_launch(void* const* d_in, const int* in_sizes, int n_in,
                              void* d_out, int out_size, void* d_ws, size_t ws_size,
                              hipStream_t stream) {
  (void)in_sizes; (void)n_in; (void)out_size; (void)ws_size;
  const float* queries = (const float*)d_in[0];
  const float* keys    = (const float*)d_in[1];
  const float* values  = (const float*)d_in[2];
  const float* mask    = (const float*)d_in[3];
  float* out = (float*)d_out;
  float* kn  = out + (size_t)N_*L_*H_*64;

  unsigned short* st = (unsigned short*)d_ws;
  short* ktil = (short*)(st + ST_SHORTS);
  short* vtilT = ktil + KV_SHORTS;
  float* mu = (float*)(vtilT + KV_SHORTS);
  float* aw = mu + NH_*L_;

  hipLaunchKernelGGL(kA,  dim3(NH_*NC_), dim3(512), 0, stream,
                     keys, values, mask, st, ktil, vtilT, mu);
  hipLaunchKernelGGL(kBC, dim3(276),     dim3(256), 0, stream, st, mu, aw);
  hipLaunchKernelGGL(kD,  dim3(NH_*NC_), dim3(512), 0, stream,
                     queries, st, ktil, vtilT, aw, out, kn);
}